// Round 10
// baseline (3452.810 us; speedup 1.0000x reference)
//
#include <hip/hip_runtime.h>
#include <hip/hip_fp16.h>
#include <hip/hip_cooperative_groups.h>

namespace cg = cooperative_groups;

#define NB     4
#define H      512
#define W      512
#define ITERS  30
#define K      4             // max iterations fused per group
#define TOLF   1e-05f
#define TOTAL  (NB*H*W*3)    // 3,145,728
#define BLK    512
#define NWAVES (BLK/64)      // 8
#define NBLKS  1024          // 4 images x 16x16 tiles of 32x32
#define HALO   8
#define EXT    48            // 32 + 2*HALO
#define LRS    48
#define LPS    (48*48)       // 2304
#define RRS    48            // rbt row stride (halfs) = 24 dwords (R18-proven)
#define RDW    24            // rbt row stride in dwords
#define RPS    (46*48)       // 2208 (46 rows)
#define NQ1    552           // stage-1 quads: 46 rows x 12 quad-cols (4 px each)
#define NB2    484           // stage-2 2x2 blocks: 22 x 22
#define NHALO  960           // halo-ring float4s: 16 rows x 36 + 32 rows x 12
#define TBIG   1000000

__device__ __forceinline__ int refl(int v, int n) {
    if (v < 0)  return -v;
    if (v >= n) return 2 * n - 2 - v;
    return v;
}

// f32 accumulate directly from f16 operand (no separate v_cvt): acc += f16(h2)*w
__device__ __forceinline__ void fmix_l(float& acc, unsigned h2, float w) {
    asm("v_fma_mix_f32 %0, %1, %2, %0 op_sel:[0,0,0] op_sel_hi:[1,0,0]"
        : "+v"(acc) : "v"(h2), "v"(w));
}
__device__ __forceinline__ void fmix_h(float& acc, unsigned h2, float w) {
    asm("v_fma_mix_f32 %0, %1, %2, %0 op_sel:[1,0,0] op_sel_hi:[1,0,0]"
        : "+v"(acc) : "v"(h2), "v"(w));
}

__device__ __forceinline__ unsigned hadd2u(unsigned a, unsigned b) {
    return __builtin_bit_cast(unsigned,
        __hadd2(__builtin_bit_cast(__half2, a), __builtin_bit_cast(__half2, b)));
}

// Vectorized row staging: each row's in-image x-span is NF4 aligned float4s.
// y-reflection folded into refl(gy) => no row-mirror fixups needed anywhere.
template<int NF4>
__device__ __forceinline__ void stage_rows(float* lat, const float* s_n,
                                           int tid, int ty0, int xlo, int jofs) {
    for (int u = tid; u < EXT * NF4; u += BLK) {
        const int i = u / NF4, q = u - i * NF4;
        const int gy = refl(ty0 - HALO + i, H);
        const float4 v = *(const float4*)(s_n + ((size_t)gy * W + xlo) * 3 + 4 * q);
        const int f = 4 * q;
        int j = jofs + f / 3;
        int c = f - 3 * (f / 3);
        const int ib = i * LRS;
        const float vv[4] = {v.x, v.y, v.z, v.w};
        #pragma unroll
        for (int e = 0; e < 4; ++e) {
            lat[c * LPS + ib + j] = vv[e];
            if (++c == 3) { c = 0; ++j; }
        }
    }
}

// Stage lat from SRCP and apply x-mirror fixup. Contains its own barriers.
#define STAGE_AND_FIX(SRCP)                                                    \
    do {                                                                       \
        const float* s_n_ = (SRCP) + nbase;                                    \
        if (!xe0 && !xe1)                                                      \
            stage_rows<36>(lat, s_n_, tid, ty0, tx0 - HALO, 0);                \
        else                                                                   \
            stage_rows<30>(lat, s_n_, tid, ty0, xe0 ? 0 : tx0 - HALO,          \
                           xe0 ? HALO : 0);                                    \
        __syncthreads();                                                       \
        if (xe0 | xe1) {                                                       \
            if (xe0) {                                                         \
                for (int p = tid; p < 3 * EXT * HALO; p += BLK) {              \
                    const int c_ = p / (EXT * HALO), rr = p - c_ * (EXT*HALO); \
                    const int i_ = rr / HALO, j_ = rr - i_ * HALO;             \
                    lat[c_ * LPS + i_ * LRS + j_] =                            \
                        lat[c_ * LPS + i_ * LRS + (16 - j_)];                  \
                }                                                              \
            } else {                                                           \
                for (int p = tid; p < 3 * EXT * HALO; p += BLK) {              \
                    const int c_ = p / (EXT * HALO), rr = p - c_ * (EXT*HALO); \
                    const int i_ = rr / HALO, j2 = rr - i_ * HALO;             \
                    lat[c_ * LPS + i_ * LRS + 40 + j2] =                       \
                        lat[c_ * LPS + i_ * LRS + (38 - j2)];                  \
                }                                                              \
            }                                                                  \
            __syncthreads();                                                   \
        }                                                                      \
    } while (0)

// Halo-ring-only restage (persistent path, non-x-edge tiles): interior [8,40)^2
// stays valid in LDS across groups (stage-2 always writes interior correctly;
// only cells outside it can hold consumed/garbage values). Ring = rows 0-7 &
// 40-47 full width (36 f4 each) + middle rows cols 0-7 / 40-47 (6+6 f4).
// All global spans 16B-aligned (tx0 mult of 32; W*3 mult of 4). refl(gy)
// handles y-edges; x-edge tiles use STAGE_AND_FIX instead.
#define HALO_STAGE(SRCP)                                                       \
    do {                                                                       \
        const float* s_n_ = (SRCP) + nbase;                                    \
        for (int u = tid; u < NHALO; u += BLK) {                               \
            int i_, q_, j0_, xlo_;                                             \
            if (u < 576) {                                                     \
                const int rr = u / 36; q_ = u - rr * 36;                       \
                i_ = (rr < 8) ? rr : rr + 32;                                  \
                j0_ = 0; xlo_ = tx0 - HALO;                                    \
            } else {                                                           \
                const int v_ = u - 576;                                        \
                const int rr = v_ / 12; const int h_ = v_ - rr * 12;           \
                i_ = rr + 8;                                                   \
                if (h_ < 6) { q_ = h_;     j0_ = 0;  xlo_ = tx0 - HALO; }      \
                else        { q_ = h_ - 6; j0_ = 40; xlo_ = tx0 + 32;  }       \
            }                                                                  \
            const int gy = refl(ty0 - HALO + i_, H);                           \
            const float4 v4 = *(const float4*)                                 \
                (s_n_ + ((size_t)gy * W + xlo_) * 3 + 4 * q_);                 \
            const int f = 4 * q_;                                              \
            int j = j0_ + f / 3;                                               \
            int c = f - 3 * (f / 3);                                           \
            const int ib = i_ * LRS;                                           \
            const float vv[4] = {v4.x, v4.y, v4.z, v4.w};                      \
            _Pragma("unroll")                                                  \
            for (int e = 0; e < 4; ++e) {                                      \
                lat[c * LPS + ib + j] = vv[e];                                 \
                if (++c == 3) { c = 0; ++j; }                                  \
            }                                                                  \
        }                                                                      \
        __syncthreads();                                                       \
    } while (0)

// Write interior [8,40)^2 from lat to dst as float4 (96 floats/row = 24 f4).
#define WRITE_INTERIOR()                                                       \
    do {                                                                       \
        for (int u = tid; u < 768; u += BLK) {                                 \
            const int i_ = u / 24, q_ = u - i_ * 24;                           \
            const int f_ = 4 * q_;                                             \
            int jj = HALO + f_ / 3;                                            \
            int c_ = f_ - 3 * (f_ / 3);                                        \
            const int ib = (i_ + HALO) * LRS;                                  \
            float v0_, v1_, v2_, v3_;                                          \
            v0_ = lat[c_ * LPS + ib + jj];                                     \
            if (++c_ == 3) { c_ = 0; ++jj; }                                   \
            v1_ = lat[c_ * LPS + ib + jj];                                     \
            if (++c_ == 3) { c_ = 0; ++jj; }                                   \
            v2_ = lat[c_ * LPS + ib + jj];                                     \
            if (++c_ == 3) { c_ = 0; ++jj; }                                   \
            v3_ = lat[c_ * LPS + ib + jj];                                     \
            *(float4*)(dst + nbase + ((size_t)(ty0 + i_) * W + tx0) * 3 + f_)  \
                = make_float4(v0_, v1_, v2_, v3_);                             \
        }                                                                      \
    } while (0)

// Stage-1 quad metadata (2 slots, R20-verified).
#define Q1META_R20()                                                           \
    do {                                                                       \
        _Pragma("unroll")                                                      \
        for (int up = 0; up < 2; ++up) {                                       \
            const int q = tid + up * BLK;                                      \
            q1mrg[up] = -1;                                                    \
            if (q < NQ1) {                                                     \
                const int i = q / 12 + 1;                                      \
                const int j = 4 * (q - (i - 1) * 12) + 1;                      \
                q1lat[up] = i * LRS + j;                                       \
                q1rb[up]  = (i - 1) * RRS + (j - 1);                           \
                const int vm = min(i - 1, 46 - i);                             \
                int cm = min(j - 1, 46 - j);                                   \
                cm = max(cm, min(j,     45 - j));                              \
                cm = max(cm, min(j + 1, 44 - j));                              \
                cm = max(cm, min(j + 2, 43 - j));                              \
                q1mrg[up] = min(vm, cm);                                       \
                const int ry = refl(ty0 - HALO + i, H);                        \
                q1o0[up] = (ry * W + refl(tx0 - HALO + j,     W)) * 3;         \
                q1o1[up] = (ry * W + refl(tx0 - HALO + j + 1, W)) * 3;         \
                q1o2[up] = (ry * W + refl(tx0 - HALO + j + 2, W)) * 3;         \
                q1o3[up] = (ry * W + refl(tx0 - HALO + j + 3, W)) * 3;         \
            }                                                                  \
        }                                                                      \
    } while (0)

// Stage-2 2x2-block metadata (R20-verified).
#define S2META_R20()                                                           \
    do {                                                                       \
        if (tid < NB2) {                                                       \
            const int R = tid / 22, C = tid - R * 22;                          \
            const int i = 2 * R + 2, j = 2 * C + 2;                            \
            s2lat_ = i * LRS + j;                                              \
            s2rb_  = 2 * R * RDW + C;                                          \
            const int mxr = max(min(i - 2, 45 - i), min(i - 1, 44 - i));       \
            const int mxc = max(min(j - 2, 45 - j), min(j - 1, 44 - j));       \
            s2mx_ = min(mxr, mxc);                                             \
            const bool i0 = ((unsigned)(i     - HALO) < 32u);                  \
            const bool i1 = ((unsigned)(i + 1 - HALO) < 32u);                  \
            const bool j0 = ((unsigned)(j     - HALO) < 32u);                  \
            const bool j1 = ((unsigned)(j + 1 - HALO) < 32u);                  \
            s2mk_ = (i0 && j0 ? 1 : 0) | (i0 && j1 ? 2 : 0)                    \
                  | (i1 && j0 ? 4 : 0) | (i1 && j1 ? 8 : 0);                   \
        }                                                                      \
    } while (0)

// Stage-1 body (R20-verified, span-4 quads, dy-symmetric).
#define S1_BODY(UP)                                                            \
    do {                                                                       \
        if (2 * s <= q1mrg[UP]) {                                              \
            const int lo = q1lat[UP];                                          \
            const int ro = q1rb[UP];                                           \
            _Pragma("unroll")                                                  \
            for (int c = 0; c < 3; ++c) {                                      \
                const float p0 = inp_n[q1o0[UP] + c];                          \
                const float p1 = inp_n[q1o1[UP] + c];                          \
                const float p2 = inp_n[q1o2[UP] + c];                          \
                const float p3 = inp_n[q1o3[UP] + c];                          \
                const float* lc = &lat[c * LPS + lo];                          \
                const float4 Fm = *(const float4*)(lc - LRS - 1);              \
                const float2 Gm = *(const float2*)(lc - LRS + 3);              \
                const float4 Fc = *(const float4*)(lc - 1);                    \
                const float2 Gc = *(const float2*)(lc + 3);                    \
                const float4 Fp = *(const float4*)(lc + LRS - 1);              \
                const float2 Gp = *(const float2*)(lc + LRS + 3);              \
                const float sx = Fm.x + Fp.x, sy = Fm.y + Fp.y;                \
                const float sz = Fm.z + Fp.z, sw = Fm.w + Fp.w;                \
                const float sgx = Gm.x + Gp.x, sgy = Gm.y + Gp.y;              \
                const float w0 = k0w[c][0], w1 = k0w[c][1], w2 = k0w[c][2];    \
                const float m0 = k1w[c][0], m1 = k1w[c][1], m2 = k1w[c][2];    \
                float a0 = fmaf(w2, sz, fmaf(w1, sy, w0 * sx));                \
                a0 = fmaf(m2, Fc.z, fmaf(m1, Fc.y, fmaf(m0, Fc.x, a0)));       \
                float a1 = fmaf(w2, sw, fmaf(w1, sz, w0 * sy));                \
                a1 = fmaf(m2, Fc.w, fmaf(m1, Fc.z, fmaf(m0, Fc.y, a1)));       \
                float a2 = fmaf(w2, sgx, fmaf(w1, sw, w0 * sz));               \
                a2 = fmaf(m2, Gc.x, fmaf(m1, Fc.w, fmaf(m0, Fc.z, a2)));       \
                float a3 = fmaf(w2, sgy, fmaf(w1, sgx, w0 * sw));              \
                a3 = fmaf(m2, Gc.y, fmaf(m1, Gc.x, fmaf(m0, Fc.w, a3)));       \
                const float r0 = p0 * __builtin_amdgcn_rcpf(a0);               \
                const float r1 = p1 * __builtin_amdgcn_rcpf(a1);               \
                const float r2 = p2 * __builtin_amdgcn_rcpf(a2);               \
                const float r3 = p3 * __builtin_amdgcn_rcpf(a3);               \
                *(__half2*)&rbt[c * RPS + ro]     = __floats2half2_rn(r0, r1); \
                *(__half2*)&rbt[c * RPS + ro + 2] = __floats2half2_rn(r2, r3); \
            }                                                                  \
        }                                                                      \
    } while (0)

// Stage-2 body (R20-verified 2x2 block). Accumulates esum.
#define S2_BODY()                                                              \
    do {                                                                       \
        if (2 * s <= s2mx_) {                                                  \
            float t00 = 0.f, t01 = 0.f, t10 = 0.f, t11 = 0.f;                  \
            _Pragma("unroll")                                                  \
            for (int c = 0; c < 3; ++c) {                                      \
                const unsigned* rp = (const unsigned*)&rbt[c * RPS] + s2rb_;   \
                const unsigned A0 = rp[0],           A1 = rp[1];               \
                const unsigned B0 = rp[RDW],         B1 = rp[RDW + 1];         \
                const unsigned C0 = rp[2 * RDW],     C1 = rp[2 * RDW + 1];     \
                const unsigned D0 = rp[3 * RDW],     D1 = rp[3 * RDW + 1];     \
                const unsigned S0 = hadd2u(A0, C0),  S1 = hadd2u(A1, C1);      \
                const unsigned T0 = hadd2u(B0, D0),  T1 = hadd2u(B1, D1);      \
                const float w0 = f0w[c][0], w1 = f0w[c][1], w2 = f0w[c][2];    \
                const float v0 = f1w[c][0], v1 = f1w[c][1], v2 = f1w[c][2];    \
                float e00 = 0.f, e01 = 0.f, e10 = 0.f, e11 = 0.f;              \
                fmix_l(e00, S0, w0); fmix_h(e00, S0, w1); fmix_l(e00, S1, w2); \
                fmix_l(e00, B0, v0); fmix_h(e00, B0, v1); fmix_l(e00, B1, v2); \
                fmix_h(e01, S0, w0); fmix_l(e01, S1, w1); fmix_h(e01, S1, w2); \
                fmix_h(e01, B0, v0); fmix_l(e01, B1, v1); fmix_h(e01, B1, v2); \
                fmix_l(e10, T0, w0); fmix_h(e10, T0, w1); fmix_l(e10, T1, w2); \
                fmix_l(e10, C0, v0); fmix_h(e10, C0, v1); fmix_l(e10, C1, v2); \
                fmix_h(e11, T0, w0); fmix_l(e11, T1, w1); fmix_h(e11, T1, w2); \
                fmix_h(e11, C0, v0); fmix_l(e11, C1, v1); fmix_h(e11, C1, v2); \
                float2* Lp0 = (float2*)&lat[c * LPS + s2lat_];                 \
                float2* Lp1 = (float2*)&lat[c * LPS + s2lat_ + LRS];           \
                float2 l0 = *Lp0, l1 = *Lp1;                                   \
                l0.x *= e00; l0.y *= e01;                                      \
                l1.x *= e10; l1.y *= e11;                                      \
                *Lp0 = l0; *Lp1 = l1;                                          \
                t00 += e00; t01 += e01; t10 += e10; t11 += e11;                \
            }                                                                  \
            esum = ((s2mk_ & 1) ? t00 : 0.f) + ((s2mk_ & 2) ? t01 : 0.f)       \
                 + ((s2mk_ & 4) ? t10 : 0.f) + ((s2mk_ & 8) ? t11 : 0.f);      \
        }                                                                      \
    } while (0)

// Convergence scan (deterministic, identical across blocks).
#define SCAN_TSTAR()                                                           \
    do {                                                                       \
        for (int t = wid; t < base; t += NWAVES) {                             \
            double a0 = 0.0, a1 = 0.0;                                         \
            for (int q = lane; q < NBLKS; q += 128) {                          \
                a0 += (double)part[t * NBLKS + q];                             \
                a1 += (double)part[t * NBLKS + q + 64];                        \
            }                                                                  \
            double a = a0 + a1;                                                \
            _Pragma("unroll")                                                  \
            for (int off = 32; off; off >>= 1) a += __shfl_down(a, off, 64);   \
            if (lane == 0) {                                                   \
                const float mean = (float)(a / (double)TOTAL);                 \
                if (fabsf(1.0f - mean) < TOLF) atomicMin(&s_tstar, t);         \
            }                                                                  \
        }                                                                      \
        __syncthreads();                                                       \
        tstar = s_tstar;                                                       \
    } while (0)

// ============================================================================
// Persistent cooperative kernel: all 9 groups in one launch, grid.sync()
// between groups. Non-x-edge tiles keep their interior in LDS across groups
// and restage only the halo ring (-44% staging). Inner loops verbatim R20.
// ============================================================================
__global__ __launch_bounds__(BLK, 8) void rl_persist(
    const float* __restrict__ inputs,
    const float* __restrict__ gk,
    const float* __restrict__ gkf,
    float* __restrict__ Abuf,
    float* __restrict__ Bbuf,
    float* __restrict__ outp,
    float* __restrict__ part)
{
    __shared__ float  lat[3 * LPS];      // 27648 B
    __shared__ __half rbt[3 * RPS];      // 13248 B
    __shared__ float  wred[NWAVES];      // 32 B
    __shared__ int    s_tstar;           // 4 B   (total 40932 <= 40960)

    const int tid  = threadIdx.x;
    const int lane = tid & 63;
    const int wid  = tid >> 6;
    const int b    = blockIdx.x;
    const int n    = b >> 8;
    const int rtile= b & 255;
    const int ty0  = (rtile >> 4) << 5;
    const int tx0  = (rtile & 15) << 5;
    const bool xe0 = (tx0 == 0), xe1 = (tx0 + 32 == W);
    const size_t nbase = (size_t)n * (H * W * 3);
    const float* inp_n = inputs + nbase;

    // hoisted kernel weights (uniform -> SGPR; dy rows 0 == 2)
    float k0w[3][3], k1w[3][3], f0w[3][3], f1w[3][3];
    #pragma unroll
    for (int c = 0; c < 3; ++c) {
        #pragma unroll
        for (int dx = 0; dx < 3; ++dx) {
            k0w[c][dx] = gk [(0 + dx) * 3 + c];
            k1w[c][dx] = gk [(3 + dx) * 3 + c];
            f0w[c][dx] = gkf[(0 + dx) * 3 + c];
            f1w[c][dx] = gkf[(3 + dx) * 3 + c];
        }
    }

    cg::grid_group grid = cg::this_grid();

    // X[g] period-3 schedule (arithmetic, NOT a runtime-indexed array —
    // rule #20): g%3==1 -> A, ==2 -> out, ==0 -> Bb; X[0]=inputs, X[8]=out.
    #pragma unroll 1
    for (int g = 0; g <= 8; ++g) {
        const int gs = (g == 8) ? 7 : g;
        const int r1 = gs % 3;
        const float* src = (gs == 0) ? inputs
                         : (r1 == 1) ? Abuf : (r1 == 2) ? outp : Bbuf;
        const int r0 = (g - 1) % 3;
        const float* sprev = (g <= 1) ? inputs
                         : (r0 == 1) ? Abuf : (r0 == 2) ? outp : Bbuf;
        const int r2 = (g + 1) % 3;
        float* dst = (g >= 8) ? outp
                   : (r2 == 1) ? Abuf : (r2 == 2) ? outp : Bbuf;
        const int base      = (4 * g < ITERS) ? 4 * g : ITERS;
        const int prev_base = (g > 0) ? 4 * (g - 1) : 0;

        // group boundary: publish prior dst/part writes, cross-XCD visible
        if (g > 0) { __threadfence(); grid.sync(); __threadfence(); }

        if (g > 0 && tid == 0) s_tstar = TBIG;
        if (g == 0) {
            STAGE_AND_FIX(src);                      // initial full stage
        } else if (g < 8) {
            if (xe0 | xe1) STAGE_AND_FIX(src);       // edge: full restage
            else           HALO_STAGE(src);          // interior kept in LDS
        } else {
            __syncthreads();                         // order s_tstar init
        }

        int tstar = TBIG;
        if (g > 0) SCAN_TSTAR();

        int m; bool wr_part;
        if (g == 0) {
            m = K; wr_part = true;
        } else if (tstar >= base) {
            if (g == 8) break;                       // out already final
            m = (ITERS - base < K) ? (ITERS - base) : K;
            wr_part = true;
        } else if (tstar >= prev_base) {
            m = tstar - prev_base + 1; wr_part = false;
            STAGE_AND_FIX(sprev);                    // rare replay path
        } else {
            if (g == 8) break;                       // out already final
            WRITE_INTERIOR();                        // lat == src interior
            continue;
        }

        // per-group metadata (kept inside loop: R21 live-range lesson)
        int q1lat[2], q1rb[2], q1mrg[2];
        int q1o0[2], q1o1[2], q1o2[2], q1o3[2];
        Q1META_R20();
        int s2lat_ = 0, s2rb_ = 0, s2mx_ = -1, s2mk_ = 0;
        S2META_R20();

        #pragma unroll
        for (int s = 0; s < K; ++s) {
            if (s >= m) break;
            S1_BODY(0);
            S1_BODY(1);
            __syncthreads();
            float esum = 0.f;
            S2_BODY();
            if (wr_part) {
                #pragma unroll
                for (int off = 32; off; off >>= 1)
                    esum += __shfl_down(esum, off, 64);
                if (lane == 0) wred[wid] = esum;
            }
            __syncthreads();
            if (wr_part && tid == 0) {
                float t = 0.f;
                #pragma unroll
                for (int w2 = 0; w2 < NWAVES; ++w2) t += wred[w2];
                part[(base + s) * NBLKS + b] = t;
            }
        }

        WRITE_INTERIOR();
    }
}

// ============================================================================
// Fallback: verified R20 multi-dispatch kernel (326.5 us), byte-identical
// logic. Used if cooperative launch is unavailable.
// ============================================================================
__global__ __launch_bounds__(BLK, 8) void rl_group(
    const float* __restrict__ inputs,
    const float* __restrict__ gk,
    const float* __restrict__ gkf,
    const float* __restrict__ src,
    const float* __restrict__ src_prev,
    float* __restrict__ dst,
    float* __restrict__ part,
    int g)
{
    __shared__ float  lat[3 * LPS];
    __shared__ __half rbt[3 * RPS];
    __shared__ float  wred[NWAVES];
    __shared__ int    s_tstar;

    const int tid  = threadIdx.x;
    const int lane = tid & 63;
    const int wid  = tid >> 6;
    const int b    = blockIdx.x;
    const int n    = b >> 8;
    const int rtile= b & 255;
    const int ty0  = (rtile >> 4) << 5;
    const int tx0  = (rtile & 15) << 5;
    const bool xe0 = (tx0 == 0), xe1 = (tx0 + 32 == W);
    const size_t nbase = (size_t)n * (H * W * 3);
    const float* inp_n = inputs + nbase;

    const int base      = (4 * g < ITERS) ? 4 * g : ITERS;
    const int prev_base = (g > 0) ? 4 * (g - 1) : 0;

    if (g > 0 && tid == 0) s_tstar = TBIG;
    if (g < 8) {
        STAGE_AND_FIX(src);
    } else {
        __syncthreads();
    }

    int tstar = TBIG;
    if (g > 0) SCAN_TSTAR();

    int m; bool wr_part;
    if (g == 0) {
        m = K; wr_part = true;
    } else if (tstar >= base) {
        if (g == 8) return;
        m = (ITERS - base < K) ? (ITERS - base) : K;
        wr_part = true;
    } else if (tstar >= prev_base) {
        m = tstar - prev_base + 1; wr_part = false;
        STAGE_AND_FIX(src_prev);
    } else {
        if (g == 8) return;
        WRITE_INTERIOR();
        return;
    }

    float k0w[3][3], k1w[3][3], f0w[3][3], f1w[3][3];
    #pragma unroll
    for (int c = 0; c < 3; ++c) {
        #pragma unroll
        for (int dx = 0; dx < 3; ++dx) {
            k0w[c][dx] = gk [(0 + dx) * 3 + c];
            k1w[c][dx] = gk [(3 + dx) * 3 + c];
            f0w[c][dx] = gkf[(0 + dx) * 3 + c];
            f1w[c][dx] = gkf[(3 + dx) * 3 + c];
        }
    }

    int q1lat[2], q1rb[2], q1mrg[2];
    int q1o0[2], q1o1[2], q1o2[2], q1o3[2];
    Q1META_R20();
    int s2lat_ = 0, s2rb_ = 0, s2mx_ = -1, s2mk_ = 0;
    S2META_R20();

    #pragma unroll
    for (int s = 0; s < K; ++s) {
        if (s >= m) break;
        S1_BODY(0);
        S1_BODY(1);
        __syncthreads();
        float esum = 0.f;
        S2_BODY();
        if (wr_part) {
            #pragma unroll
            for (int off = 32; off; off >>= 1)
                esum += __shfl_down(esum, off, 64);
            if (lane == 0) wred[wid] = esum;
        }
        __syncthreads();
        if (wr_part && tid == 0) {
            float t = 0.f;
            #pragma unroll
            for (int w2 = 0; w2 < NWAVES; ++w2) t += wred[w2];
            part[(base + s) * NBLKS + b] = t;
        }
    }

    WRITE_INTERIOR();
}

extern "C" void kernel_launch(void* const* d_in, const int* in_sizes, int n_in,
                              void* d_out, int out_size, void* d_ws, size_t ws_size,
                              hipStream_t stream) {
    const float* inputs = (const float*)d_in[0];
    const float* gk     = (const float*)d_in[1];
    const float* gkf    = (const float*)d_in[2];
    float* out = (float*)d_out;

    // ws: [0 .. 128KB) iteration partials [30][1024] | buffer A | buffer B
    char* ws = (char*)d_ws;
    float* part = (float*)ws;
    float* A    = (float*)(ws + 131072);
    float* Bb   = (float*)(ws + 131072 + (size_t)TOTAL * sizeof(float));

    // Cooperative persistent path: 1024 blocks = exactly 4/CU x 256 CU.
    const float* a0 = inputs; const float* a1 = gk; const float* a2 = gkf;
    float* a3 = A; float* a4 = Bb; float* a5 = out; float* a6 = part;
    void* args[] = { &a0, &a1, &a2, &a3, &a4, &a5, &a6 };
    hipError_t err = hipLaunchCooperativeKernel(
        reinterpret_cast<const void*>(&rl_persist),
        dim3(NBLKS), dim3(BLK), args, 0u, stream);

    if (err != hipSuccess) {
        (void)hipGetLastError();   // clear; fall back to verified R20 path
        const float* X[9] = { inputs, A, out, Bb, A, out, Bb, A, out };
        for (int g = 0; g < 9; ++g) {
            const float* s  = X[(g == 8) ? 7 : g];
            const float* sp = X[(g == 0) ? 0 : g - 1];
            float*       d  = (float*)((g == 8) ? X[8] : X[g + 1]);
            rl_group<<<NBLKS, BLK, 0, stream>>>(inputs, gk, gkf, s, sp, d, part, g);
        }
    }
}

// Round 11
// 294.341 us; speedup vs baseline: 11.7307x; 11.7307x over previous
//
#include <hip/hip_runtime.h>
#include <hip/hip_fp16.h>

#define NB     4
#define H      512
#define W      512
#define ITERS  30
#define K      4             // max iterations fused per dispatch
#define TOLF   1e-05f
#define TOTAL  (NB*H*W*3)    // 3,145,728
#define BLK    512
#define NWAVES (BLK/64)      // 8
#define NBLKS  1024          // 4 images x 16x16 tiles of 32x32
#define HALO   8
#define EXT    48            // 32 + 2*HALO
#define LRS    48
#define LPS    (48*48)       // 2304
#define RRS    48            // rbt row stride (halfs) = 24 dwords (R18-proven)
#define RDW    24            // rbt row stride in dwords
#define RPS    (46*48)       // 2208 (46 rows)
#define NQ1    552           // stage-1 quads: 46 rows x 12 quad-cols (4 px each)
#define NB2    484           // stage-2 2x2 blocks: 22 x 22
#define TBIG   1000000

__device__ __forceinline__ int refl(int v, int n) {
    if (v < 0)  return -v;
    if (v >= n) return 2 * n - 2 - v;
    return v;
}

// f32 accumulate directly from f16 operand (no separate v_cvt): acc += f16(h2)*w
__device__ __forceinline__ void fmix_l(float& acc, unsigned h2, float w) {
    asm("v_fma_mix_f32 %0, %1, %2, %0 op_sel:[0,0,0] op_sel_hi:[1,0,0]"
        : "+v"(acc) : "v"(h2), "v"(w));
}
__device__ __forceinline__ void fmix_h(float& acc, unsigned h2, float w) {
    asm("v_fma_mix_f32 %0, %1, %2, %0 op_sel:[1,0,0] op_sel_hi:[1,0,0]"
        : "+v"(acc) : "v"(h2), "v"(w));
}

__device__ __forceinline__ unsigned hadd2u(unsigned a, unsigned b) {
    return __builtin_bit_cast(unsigned,
        __hadd2(__builtin_bit_cast(__half2, a), __builtin_bit_cast(__half2, b)));
}

// Vectorized row staging: each row's in-image x-span is NF4 aligned float4s.
// y-reflection folded into refl(gy) => no row-mirror fixups needed anywhere.
template<int NF4>
__device__ __forceinline__ void stage_rows(float* lat, const float* s_n,
                                           int tid, int ty0, int xlo, int jofs) {
    for (int u = tid; u < EXT * NF4; u += BLK) {
        const int i = u / NF4, q = u - i * NF4;
        const int gy = refl(ty0 - HALO + i, H);
        const float4 v = *(const float4*)(s_n + ((size_t)gy * W + xlo) * 3 + 4 * q);
        const int f = 4 * q;
        int j = jofs + f / 3;
        int c = f - 3 * (f / 3);
        const int ib = i * LRS;
        const float vv[4] = {v.x, v.y, v.z, v.w};
        #pragma unroll
        for (int e = 0; e < 4; ++e) {
            lat[c * LPS + ib + j] = vv[e];
            if (++c == 3) { c = 0; ++j; }
        }
    }
}

// Stage lat from SRCP and apply x-mirror fixup. Contains its own barriers.
#define STAGE_AND_FIX(SRCP)                                                    \
    do {                                                                       \
        const float* s_n_ = (SRCP) + nbase;                                    \
        if (!xe0 && !xe1)                                                      \
            stage_rows<36>(lat, s_n_, tid, ty0, tx0 - HALO, 0);                \
        else                                                                   \
            stage_rows<30>(lat, s_n_, tid, ty0, xe0 ? 0 : tx0 - HALO,          \
                           xe0 ? HALO : 0);                                    \
        __syncthreads();                                                       \
        if (xe0 | xe1) {                                                       \
            if (xe0) {                                                         \
                for (int p = tid; p < 3 * EXT * HALO; p += BLK) {              \
                    const int c_ = p / (EXT * HALO), rr = p - c_ * (EXT*HALO); \
                    const int i_ = rr / HALO, j_ = rr - i_ * HALO;             \
                    lat[c_ * LPS + i_ * LRS + j_] =                            \
                        lat[c_ * LPS + i_ * LRS + (16 - j_)];                  \
                }                                                              \
            } else {                                                           \
                for (int p = tid; p < 3 * EXT * HALO; p += BLK) {              \
                    const int c_ = p / (EXT * HALO), rr = p - c_ * (EXT*HALO); \
                    const int i_ = rr / HALO, j2 = rr - i_ * HALO;             \
                    lat[c_ * LPS + i_ * LRS + 40 + j2] =                       \
                        lat[c_ * LPS + i_ * LRS + (38 - j2)];                  \
                }                                                              \
            }                                                                  \
            __syncthreads();                                                   \
        }                                                                      \
    } while (0)

// Write interior [8,40)^2 from lat to dst as float4 (96 floats/row = 24 f4).
#define WRITE_INTERIOR()                                                       \
    do {                                                                       \
        for (int u = tid; u < 768; u += BLK) {                                 \
            const int i_ = u / 24, q_ = u - i_ * 24;                           \
            const int f_ = 4 * q_;                                             \
            int jj = HALO + f_ / 3;                                            \
            int c_ = f_ - 3 * (f_ / 3);                                        \
            const int ib = (i_ + HALO) * LRS;                                  \
            float v0_, v1_, v2_, v3_;                                          \
            v0_ = lat[c_ * LPS + ib + jj];                                     \
            if (++c_ == 3) { c_ = 0; ++jj; }                                   \
            v1_ = lat[c_ * LPS + ib + jj];                                     \
            if (++c_ == 3) { c_ = 0; ++jj; }                                   \
            v2_ = lat[c_ * LPS + ib + jj];                                     \
            if (++c_ == 3) { c_ = 0; ++jj; }                                   \
            v3_ = lat[c_ * LPS + ib + jj];                                     \
            *(float4*)(dst + nbase + ((size_t)(ty0 + i_) * W + tx0) * 3 + f_)  \
                = make_float4(v0_, v1_, v2_, v3_);                             \
        }                                                                      \
    } while (0)

// One dispatch = up to K=4 fused RL iterations on a 32x32 tile, halo-8.
// R25 = R20 (326.5 us, best verified) + INCREMENTAL convergence scan:
//  - group g scans only the K=4 part[] rows written by group g-1
//    ([prev_base, base)) and combines with a running minimum persisted at
//    part+30*1024 (spare ws word; dispatch ordering makes g-1's write
//    visible). Replaces the O(g) full rescan — at g=7 that was 28 serial
//    1024-float reductions, outgrowing its staging overlap (R18 mechanism).
//  - determinism: per-t reduction order unchanged; all blocks write the
//    same running-min value; g=1 seeds TBIG (no cross-run staleness).
//  - early-convergence safety: if t* fired before the window, stored min
//    dominates any unwritten-window garbage (same argument as full scan).
// R24's cooperative persistent kernel REVERTED: grid.sync() costs ~400us
// on gfx950 @1024 blocks — dispatch boundaries ARE the cheap grid barrier.
// Everything else byte-identical to R20.
__global__ __launch_bounds__(BLK, 8) void rl_group(
    const float* __restrict__ inputs,
    const float* __restrict__ gk,
    const float* __restrict__ gkf,
    const float* __restrict__ src,       // latent at group start
    const float* __restrict__ src_prev,  // latent at PREVIOUS group start
    float* __restrict__ dst,
    float* __restrict__ part,            // [30][1024] iteration partials
    int g)                               // 0..7 compute, 8 fixup
{
    __shared__ float  lat[3 * LPS];      // 27648 B
    __shared__ __half rbt[3 * RPS];      // 13248 B
    __shared__ float  wred[NWAVES];      // 32 B
    __shared__ int    s_tstar;           // 4 B   (total 40932 <= 40960)

    const int tid  = threadIdx.x;
    const int lane = tid & 63;
    const int wid  = tid >> 6;
    const int b    = blockIdx.x;
    const int n    = b >> 8;
    const int rtile= b & 255;
    const int ty0  = (rtile >> 4) << 5;
    const int tx0  = (rtile & 15) << 5;
    const bool xe0 = (tx0 == 0), xe1 = (tx0 + 32 == W);
    const size_t nbase = (size_t)n * (H * W * 3);
    const float* inp_n = inputs + nbase;

    const int base      = (4 * g < ITERS) ? 4 * g : ITERS;
    const int prev_base = (g > 0) ? 4 * (g - 1) : 0;

    // running first-firing-iteration minimum, persisted across dispatches
    int* tmin_g = (int*)(part + 30 * NBLKS);

    // ---- stage src tile first (g<8); scan overlaps it below ----
    if (g > 0 && tid == 0) s_tstar = (g >= 2) ? *tmin_g : TBIG;
    if (g < 8) {
        STAGE_AND_FIX(src);              // contains the barrier after staging
    } else {
        __syncthreads();                 // orders s_tstar init before scan
    }

    // ---- incremental scan: only the window [prev_base, base) is new ----
    int tstar = TBIG;
    if (g > 0) {
        for (int t = prev_base + wid; t < base; t += NWAVES) {
            double a0 = 0.0, a1 = 0.0;
            for (int q = lane; q < NBLKS; q += 128) {
                a0 += (double)part[t * NBLKS + q];
                a1 += (double)part[t * NBLKS + q + 64];
            }
            double a = a0 + a1;
            #pragma unroll
            for (int off = 32; off; off >>= 1) a += __shfl_down(a, off, 64);
            if (lane == 0) {
                const float mean = (float)(a / (double)TOTAL);
                if (fabsf(1.0f - mean) < TOLF) atomicMin(&s_tstar, t);
            }
        }
        __syncthreads();
        tstar = s_tstar;
        if (g < 8 && tid == 0) *tmin_g = tstar;   // same value from all blocks
    }

    // ---- mode decision (block-uniform, identical across all blocks) ----
    int m;
    bool wr_part;
    if (g == 0) {
        m = K; wr_part = true;                       // lat already = src
    } else if (tstar >= base) {
        if (g == 8) return;
        m = (ITERS - base < K) ? (ITERS - base) : K;
        wr_part = true;                              // lat already = src
    } else if (tstar >= prev_base) {
        m = tstar - prev_base + 1; wr_part = false;
        STAGE_AND_FIX(src_prev);                     // restage (rare; g==8: first stage)
    } else {
        if (g == 8) return;
        WRITE_INTERIOR();                            // lat == src interior
        return;
    }

    // ---- hoisted kernel weights (uniform). dy rows 0 == 2. ----
    float k0w[3][3], k1w[3][3], f0w[3][3], f1w[3][3];
    #pragma unroll
    for (int c = 0; c < 3; ++c) {
        #pragma unroll
        for (int dx = 0; dx < 3; ++dx) {
            k0w[c][dx] = gk [(0 + dx) * 3 + c];
            k1w[c][dx] = gk [(3 + dx) * 3 + c];
            f0w[c][dx] = gkf[(0 + dx) * 3 + c];
            f1w[c][dx] = gkf[(3 + dx) * 3 + c];
        }
    }

    // ---- stage-1 quad metadata (2 slots, verbatim R20) ----
    // quad q: i = q/12 + 1 in [1,47), j = 4*(q%12) + 1 (== 1 mod 4)
    int q1lat[2], q1rb[2], q1mrg[2];
    int q1o0[2], q1o1[2], q1o2[2], q1o3[2];
    #pragma unroll
    for (int up = 0; up < 2; ++up) {
        const int q = tid + up * BLK;
        q1mrg[up] = -1;
        if (q < NQ1) {
            const int i = q / 12 + 1;
            const int j = 4 * (q - (i - 1) * 12) + 1;
            q1lat[up] = i * LRS + j;
            q1rb[up]  = (i - 1) * RRS + (j - 1);
            const int vm = min(i - 1, 46 - i);
            int cm = min(j - 1, 46 - j);
            cm = max(cm, min(j,     45 - j));
            cm = max(cm, min(j + 1, 44 - j));
            cm = max(cm, min(j + 2, 43 - j));
            q1mrg[up] = min(vm, cm);
            const int ry = refl(ty0 - HALO + i, H);
            q1o0[up] = (ry * W + refl(tx0 - HALO + j,     W)) * 3;
            q1o1[up] = (ry * W + refl(tx0 - HALO + j + 1, W)) * 3;
            q1o2[up] = (ry * W + refl(tx0 - HALO + j + 2, W)) * 3;
            q1o3[up] = (ry * W + refl(tx0 - HALO + j + 3, W)) * 3;
        }
    }

    // ---- stage-2 2x2-block metadata: R,C in [0,22); i = 2R+2, j = 2C+2 ----
    // rb window rows 2R..2R+3, dwords d = 48R + C, d+1 (cols j-2..j+1).
    int s2lat_ = 0, s2rb_ = 0, s2mx_ = -1, s2mk_ = 0;
    if (tid < NB2) {
        const int R = tid / 22, C = tid - R * 22;
        const int i = 2 * R + 2, j = 2 * C + 2;
        s2lat_ = i * LRS + j;
        s2rb_  = 2 * R * RDW + C;        // dword index into rbt plane
        const int mxr = max(min(i - 2, 45 - i), min(i - 1, 44 - i));
        const int mxc = max(min(j - 2, 45 - j), min(j - 1, 44 - j));
        s2mx_ = min(mxr, mxc);
        const bool i0 = ((unsigned)(i     - HALO) < 32u);
        const bool i1 = ((unsigned)(i + 1 - HALO) < 32u);
        const bool j0 = ((unsigned)(j     - HALO) < 32u);
        const bool j1 = ((unsigned)(j + 1 - HALO) < 32u);
        s2mk_ = (i0 && j0 ? 1 : 0) | (i0 && j1 ? 2 : 0)
              | (i1 && j0 ? 4 : 0) | (i1 && j1 ? 8 : 0);
    }

    // ---- fused sub-iterations (2 barriers each) ----
    #pragma unroll
    for (int s = 0; s < K; ++s) {
        if (s >= m) break;

        // stage 1: rb = inp * rcp(conv(lat, k)) — span-4 quads, dy-symmetric:
        // rows i-1 and i+1 pre-summed (gk row0 == row2), 6 mult/px.
        #pragma unroll
        for (int up = 0; up < 2; ++up) {
            if (2 * s <= q1mrg[up]) {
                const int lo = q1lat[up];
                const int ro = q1rb[up];
                #pragma unroll
                for (int c = 0; c < 3; ++c) {
                    const float p0 = inp_n[q1o0[up] + c];
                    const float p1 = inp_n[q1o1[up] + c];
                    const float p2 = inp_n[q1o2[up] + c];
                    const float p3 = inp_n[q1o3[up] + c];
                    const float* lc = &lat[c * LPS + lo];
                    const float4 Fm = *(const float4*)(lc - LRS - 1);
                    const float2 Gm = *(const float2*)(lc - LRS + 3);
                    const float4 Fc = *(const float4*)(lc - 1);
                    const float2 Gc = *(const float2*)(lc + 3);
                    const float4 Fp = *(const float4*)(lc + LRS - 1);
                    const float2 Gp = *(const float2*)(lc + LRS + 3);
                    const float sx = Fm.x + Fp.x, sy = Fm.y + Fp.y;
                    const float sz = Fm.z + Fp.z, sw = Fm.w + Fp.w;
                    const float sgx = Gm.x + Gp.x, sgy = Gm.y + Gp.y;
                    const float w0 = k0w[c][0], w1 = k0w[c][1], w2 = k0w[c][2];
                    const float m0 = k1w[c][0], m1 = k1w[c][1], m2 = k1w[c][2];
                    float a0 = fmaf(w2, sz, fmaf(w1, sy, w0 * sx));
                    a0 = fmaf(m2, Fc.z, fmaf(m1, Fc.y, fmaf(m0, Fc.x, a0)));
                    float a1 = fmaf(w2, sw, fmaf(w1, sz, w0 * sy));
                    a1 = fmaf(m2, Fc.w, fmaf(m1, Fc.z, fmaf(m0, Fc.y, a1)));
                    float a2 = fmaf(w2, sgx, fmaf(w1, sw, w0 * sz));
                    a2 = fmaf(m2, Gc.x, fmaf(m1, Fc.w, fmaf(m0, Fc.z, a2)));
                    float a3 = fmaf(w2, sgy, fmaf(w1, sgx, w0 * sw));
                    a3 = fmaf(m2, Gc.y, fmaf(m1, Gc.x, fmaf(m0, Fc.w, a3)));
                    const float r0 = p0 * __builtin_amdgcn_rcpf(a0);
                    const float r1 = p1 * __builtin_amdgcn_rcpf(a1);
                    const float r2 = p2 * __builtin_amdgcn_rcpf(a2);
                    const float r3 = p3 * __builtin_amdgcn_rcpf(a3);
                    *(__half2*)&rbt[c * RPS + ro]     = __floats2half2_rn(r0, r1);
                    *(__half2*)&rbt[c * RPS + ro + 2] = __floats2half2_rn(r2, r3);
                }
            }
        }
        __syncthreads();

        // stage 2: e = conv(rb, kf); lat *= e; esum over interior.
        // 2x2 block: rb rows A,B,Cc,D (4 consecutive), dwords d,d+1 each.
        // Out row i:   dy-sum S = A + Cc (gkf row0==row2), mid = B.
        // Out row i+1: dy-sum T = B + D,                   mid = Cc.
        float esum = 0.f;
        if (2 * s <= s2mx_) {
            float t00 = 0.f, t01 = 0.f, t10 = 0.f, t11 = 0.f;
            #pragma unroll
            for (int c = 0; c < 3; ++c) {
                const unsigned* rp = (const unsigned*)&rbt[c * RPS] + s2rb_;
                const unsigned A0 = rp[0],           A1 = rp[1];
                const unsigned B0 = rp[RDW],         B1 = rp[RDW + 1];
                const unsigned C0 = rp[2 * RDW],     C1 = rp[2 * RDW + 1];
                const unsigned D0 = rp[3 * RDW],     D1 = rp[3 * RDW + 1];
                const unsigned S0 = hadd2u(A0, C0),  S1 = hadd2u(A1, C1);
                const unsigned T0 = hadd2u(B0, D0),  T1 = hadd2u(B1, D1);
                const float w0 = f0w[c][0], w1 = f0w[c][1], w2 = f0w[c][2];
                const float v0 = f1w[c][0], v1 = f1w[c][1], v2 = f1w[c][2];
                float e00 = 0.f, e01 = 0.f, e10 = 0.f, e11 = 0.f;
                fmix_l(e00, S0, w0); fmix_h(e00, S0, w1); fmix_l(e00, S1, w2);
                fmix_l(e00, B0, v0); fmix_h(e00, B0, v1); fmix_l(e00, B1, v2);
                fmix_h(e01, S0, w0); fmix_l(e01, S1, w1); fmix_h(e01, S1, w2);
                fmix_h(e01, B0, v0); fmix_l(e01, B1, v1); fmix_h(e01, B1, v2);
                fmix_l(e10, T0, w0); fmix_h(e10, T0, w1); fmix_l(e10, T1, w2);
                fmix_l(e10, C0, v0); fmix_h(e10, C0, v1); fmix_l(e10, C1, v2);
                fmix_h(e11, T0, w0); fmix_l(e11, T1, w1); fmix_h(e11, T1, w2);
                fmix_h(e11, C0, v0); fmix_l(e11, C1, v1); fmix_h(e11, C1, v2);
                float2* Lp0 = (float2*)&lat[c * LPS + s2lat_];
                float2* Lp1 = (float2*)&lat[c * LPS + s2lat_ + LRS];
                float2 l0 = *Lp0, l1 = *Lp1;
                l0.x *= e00; l0.y *= e01;
                l1.x *= e10; l1.y *= e11;
                *Lp0 = l0; *Lp1 = l1;
                t00 += e00; t01 += e01; t10 += e10; t11 += e11;
            }
            esum = ((s2mk_ & 1) ? t00 : 0.f) + ((s2mk_ & 2) ? t01 : 0.f)
                 + ((s2mk_ & 4) ? t10 : 0.f) + ((s2mk_ & 8) ? t11 : 0.f);
        }
        if (wr_part) {
            #pragma unroll
            for (int off = 32; off; off >>= 1) esum += __shfl_down(esum, off, 64);
            if (lane == 0) wred[wid] = esum;
        }
        __syncthreads();     // lat writes done AND wred ready
        if (wr_part && tid == 0) {
            float t = 0.f;
            #pragma unroll
            for (int w2 = 0; w2 < NWAVES; ++w2) t += wred[w2];
            part[(base + s) * NBLKS + b] = t;
        }
    }

    // ---- write interior [8,40)^2 to dst ----
    WRITE_INTERIOR();
}

extern "C" void kernel_launch(void* const* d_in, const int* in_sizes, int n_in,
                              void* d_out, int out_size, void* d_ws, size_t ws_size,
                              hipStream_t stream) {
    const float* inputs = (const float*)d_in[0];
    const float* gk     = (const float*)d_in[1];
    const float* gkf    = (const float*)d_in[2];
    float* out = (float*)d_out;

    // ws: [0 .. 128KB) iteration partials [30][1024] + running tmin word
    //     | buffer A | buffer B
    char* ws = (char*)d_ws;
    float* part = (float*)ws;
    float* A    = (float*)(ws + 131072);
    float* Bb   = (float*)(ws + 131072 + (size_t)TOTAL * sizeof(float));

    // period-3 schedule; X[g] = latent at start of group g. X[8] = out.
    const float* X[9] = { inputs, A, out, Bb, A, out, Bb, A, out };

    for (int g = 0; g < 9; ++g) {
        const float* s  = X[(g == 8) ? 7 : g];
        const float* sp = X[(g == 0) ? 0 : g - 1];
        float*       d  = (float*)((g == 8) ? X[8] : X[g + 1]);
        rl_group<<<NBLKS, BLK, 0, stream>>>(inputs, gk, gkf, s, sp, d, part, g);
    }
}

// Round 12
// 293.100 us; speedup vs baseline: 11.7803x; 1.0042x over previous
//
#include <hip/hip_runtime.h>
#include <hip/hip_fp16.h>

#define NB     4
#define H      512
#define W      512
#define ITERS  30
#define K      4             // max iterations fused per dispatch
#define TOLF   1e-05f
#define TOTAL  (NB*H*W*3)    // 3,145,728
#define BLK    512
#define NWAVES (BLK/64)      // 8
#define NBLKS  1024          // 4 images x 16x16 tiles of 32x32
#define HALO   8
#define EXT    48            // 32 + 2*HALO
#define LRS    48
#define LPS    (48*48)       // 2304
#define RRS    48            // rbt row stride (halfs) = 24 dwords (R18-proven)
#define RDW    24            // rbt row stride in dwords
#define RPS    (46*48)       // 2208 (46 rows)
#define NQ1    552           // stage-1 quads: 46 rows x 12 quad-cols (4 px each)
#define NB2    484           // stage-2 2x2 blocks: 22 x 22
#define TBIG   1000000

__device__ __forceinline__ int refl(int v, int n) {
    if (v < 0)  return -v;
    if (v >= n) return 2 * n - 2 - v;
    return v;
}

// f32 accumulate directly from f16 operand (no separate v_cvt): acc += f16(h2)*w
__device__ __forceinline__ void fmix_l(float& acc, unsigned h2, float w) {
    asm("v_fma_mix_f32 %0, %1, %2, %0 op_sel:[0,0,0] op_sel_hi:[1,0,0]"
        : "+v"(acc) : "v"(h2), "v"(w));
}
__device__ __forceinline__ void fmix_h(float& acc, unsigned h2, float w) {
    asm("v_fma_mix_f32 %0, %1, %2, %0 op_sel:[1,0,0] op_sel_hi:[1,0,0]"
        : "+v"(acc) : "v"(h2), "v"(w));
}

__device__ __forceinline__ unsigned hadd2u(unsigned a, unsigned b) {
    return __builtin_bit_cast(unsigned,
        __hadd2(__builtin_bit_cast(__half2, a), __builtin_bit_cast(__half2, b)));
}

// Quad-vectorized row staging: each unit = 4 pixels (12 floats) = 3 aligned
// global float4 loads -> register transpose -> 3 aligned LDS b128 stores
// (one per channel plane). Replaces 3 loads + 12 scalar ds_write_b32 per
// 4 px (R26): LDS writes 6912 b32 -> 1728 b128 per block-stage, loop trips
// /3. y-reflection folded into refl(gy); alignment: jofs+4q == 0 mod 4 for
// all tile classes, global bases == 0 mod 4 floats.
template<int NPQ>   // pixel-quads per row: 12 (interior) or 10 (x-edge)
__device__ __forceinline__ void stage_rows_q(float* lat, const float* s_n,
                                             int tid, int ty0, int xlo, int jofs) {
    for (int u = tid; u < EXT * NPQ; u += BLK) {
        const int i = u / NPQ, q = u - i * NPQ;
        const int gy = refl(ty0 - HALO + i, H);
        const float* gp = s_n + ((size_t)gy * W + xlo) * 3 + 12 * q;
        const float4 v0 = *(const float4*)(gp);
        const float4 v1 = *(const float4*)(gp + 4);
        const float4 v2 = *(const float4*)(gp + 8);
        const int o = i * LRS + jofs + 4 * q;
        *(float4*)&lat[o]           = make_float4(v0.x, v0.w, v1.z, v2.y);
        *(float4*)&lat[LPS + o]     = make_float4(v0.y, v1.x, v1.w, v2.z);
        *(float4*)&lat[2 * LPS + o] = make_float4(v0.z, v1.y, v2.x, v2.w);
    }
}

// Stage lat from SRCP and apply x-mirror fixup. Contains its own barriers.
#define STAGE_AND_FIX(SRCP)                                                    \
    do {                                                                       \
        const float* s_n_ = (SRCP) + nbase;                                    \
        if (!xe0 && !xe1)                                                      \
            stage_rows_q<12>(lat, s_n_, tid, ty0, tx0 - HALO, 0);              \
        else                                                                   \
            stage_rows_q<10>(lat, s_n_, tid, ty0, xe0 ? 0 : tx0 - HALO,        \
                             xe0 ? HALO : 0);                                  \
        __syncthreads();                                                       \
        if (xe0 | xe1) {                                                       \
            if (xe0) {                                                         \
                for (int p = tid; p < 3 * EXT * HALO; p += BLK) {              \
                    const int c_ = p / (EXT * HALO), rr = p - c_ * (EXT*HALO); \
                    const int i_ = rr / HALO, j_ = rr - i_ * HALO;             \
                    lat[c_ * LPS + i_ * LRS + j_] =                            \
                        lat[c_ * LPS + i_ * LRS + (16 - j_)];                  \
                }                                                              \
            } else {                                                           \
                for (int p = tid; p < 3 * EXT * HALO; p += BLK) {              \
                    const int c_ = p / (EXT * HALO), rr = p - c_ * (EXT*HALO); \
                    const int i_ = rr / HALO, j2 = rr - i_ * HALO;             \
                    lat[c_ * LPS + i_ * LRS + 40 + j2] =                       \
                        lat[c_ * LPS + i_ * LRS + (38 - j2)];                  \
                }                                                              \
            }                                                                  \
            __syncthreads();                                                   \
        }                                                                      \
    } while (0)

// Write interior [8,40)^2 from lat to dst: 4-px quads, 3 b128 LDS reads
// (one per plane) + register transpose + 3 aligned global float4 stores.
// 256 units (8 quads/row x 32 rows); replaces 768 x 4 scalar ds_read_b32.
#define WRITE_INTERIOR()                                                       \
    do {                                                                       \
        for (int u = tid; u < 256; u += BLK) {                                 \
            const int i_ = u >> 3, q_ = u & 7;                                 \
            const int o = (i_ + HALO) * LRS + HALO + 4 * q_;                   \
            const float4 a  = *(const float4*)&lat[o];                         \
            const float4 bv = *(const float4*)&lat[LPS + o];                   \
            const float4 cv = *(const float4*)&lat[2 * LPS + o];               \
            float* gp = dst + nbase                                            \
                      + ((size_t)(ty0 + i_) * W + tx0 + 4 * q_) * 3;           \
            *(float4*)(gp)     = make_float4(a.x,  bv.x, cv.x, a.y);           \
            *(float4*)(gp + 4) = make_float4(bv.y, cv.y, a.z,  bv.z);          \
            *(float4*)(gp + 8) = make_float4(cv.z, a.w,  bv.w, cv.w);          \
        }                                                                      \
    } while (0)

// One dispatch = up to K=4 fused RL iterations on a 32x32 tile, halo-8.
// R26 = R25 (294.3 us, best verified) + vectorized AoS<->SoA boundary:
//  - staging: 4-px/12-float units, 3 global f4 + 3 LDS b128 per unit
//    (was 1 f4 + 4 scalar b32 per 4/3 px): LDS write instrs /4, loop
//    overhead /3. b128 store pattern ~2-way bank aliasing (free, m136).
//  - interior writeback: same quad transpose in reverse (768 b128 reads
//    vs 3072 b32). Register transpose lives only inside the unit body —
//    no s-loop live-range growth (R21-R23 lesson).
// R25's incremental scan + R20 inner loops byte-identical.
__global__ __launch_bounds__(BLK, 8) void rl_group(
    const float* __restrict__ inputs,
    const float* __restrict__ gk,
    const float* __restrict__ gkf,
    const float* __restrict__ src,       // latent at group start
    const float* __restrict__ src_prev,  // latent at PREVIOUS group start
    float* __restrict__ dst,
    float* __restrict__ part,            // [30][1024] iteration partials
    int g)                               // 0..7 compute, 8 fixup
{
    __shared__ float  lat[3 * LPS];      // 27648 B
    __shared__ __half rbt[3 * RPS];      // 13248 B
    __shared__ float  wred[NWAVES];      // 32 B
    __shared__ int    s_tstar;           // 4 B   (total 40932 <= 40960)

    const int tid  = threadIdx.x;
    const int lane = tid & 63;
    const int wid  = tid >> 6;
    const int b    = blockIdx.x;
    const int n    = b >> 8;
    const int rtile= b & 255;
    const int ty0  = (rtile >> 4) << 5;
    const int tx0  = (rtile & 15) << 5;
    const bool xe0 = (tx0 == 0), xe1 = (tx0 + 32 == W);
    const size_t nbase = (size_t)n * (H * W * 3);
    const float* inp_n = inputs + nbase;

    const int base      = (4 * g < ITERS) ? 4 * g : ITERS;
    const int prev_base = (g > 0) ? 4 * (g - 1) : 0;

    // running first-firing-iteration minimum, persisted across dispatches
    int* tmin_g = (int*)(part + 30 * NBLKS);

    // ---- stage src tile first (g<8); scan overlaps it below ----
    if (g > 0 && tid == 0) s_tstar = (g >= 2) ? *tmin_g : TBIG;
    if (g < 8) {
        STAGE_AND_FIX(src);              // contains the barrier after staging
    } else {
        __syncthreads();                 // orders s_tstar init before scan
    }

    // ---- incremental scan: only the window [prev_base, base) is new ----
    int tstar = TBIG;
    if (g > 0) {
        for (int t = prev_base + wid; t < base; t += NWAVES) {
            double a0 = 0.0, a1 = 0.0;
            for (int q = lane; q < NBLKS; q += 128) {
                a0 += (double)part[t * NBLKS + q];
                a1 += (double)part[t * NBLKS + q + 64];
            }
            double a = a0 + a1;
            #pragma unroll
            for (int off = 32; off; off >>= 1) a += __shfl_down(a, off, 64);
            if (lane == 0) {
                const float mean = (float)(a / (double)TOTAL);
                if (fabsf(1.0f - mean) < TOLF) atomicMin(&s_tstar, t);
            }
        }
        __syncthreads();
        tstar = s_tstar;
        if (g < 8 && tid == 0) *tmin_g = tstar;   // same value from all blocks
    }

    // ---- mode decision (block-uniform, identical across all blocks) ----
    int m;
    bool wr_part;
    if (g == 0) {
        m = K; wr_part = true;                       // lat already = src
    } else if (tstar >= base) {
        if (g == 8) return;
        m = (ITERS - base < K) ? (ITERS - base) : K;
        wr_part = true;                              // lat already = src
    } else if (tstar >= prev_base) {
        m = tstar - prev_base + 1; wr_part = false;
        STAGE_AND_FIX(src_prev);                     // restage (rare; g==8: first stage)
    } else {
        if (g == 8) return;
        WRITE_INTERIOR();                            // lat == src interior
        return;
    }

    // ---- hoisted kernel weights (uniform). dy rows 0 == 2. ----
    float k0w[3][3], k1w[3][3], f0w[3][3], f1w[3][3];
    #pragma unroll
    for (int c = 0; c < 3; ++c) {
        #pragma unroll
        for (int dx = 0; dx < 3; ++dx) {
            k0w[c][dx] = gk [(0 + dx) * 3 + c];
            k1w[c][dx] = gk [(3 + dx) * 3 + c];
            f0w[c][dx] = gkf[(0 + dx) * 3 + c];
            f1w[c][dx] = gkf[(3 + dx) * 3 + c];
        }
    }

    // ---- stage-1 quad metadata (2 slots, verbatim R20) ----
    // quad q: i = q/12 + 1 in [1,47), j = 4*(q%12) + 1 (== 1 mod 4)
    int q1lat[2], q1rb[2], q1mrg[2];
    int q1o0[2], q1o1[2], q1o2[2], q1o3[2];
    #pragma unroll
    for (int up = 0; up < 2; ++up) {
        const int q = tid + up * BLK;
        q1mrg[up] = -1;
        if (q < NQ1) {
            const int i = q / 12 + 1;
            const int j = 4 * (q - (i - 1) * 12) + 1;
            q1lat[up] = i * LRS + j;
            q1rb[up]  = (i - 1) * RRS + (j - 1);
            const int vm = min(i - 1, 46 - i);
            int cm = min(j - 1, 46 - j);
            cm = max(cm, min(j,     45 - j));
            cm = max(cm, min(j + 1, 44 - j));
            cm = max(cm, min(j + 2, 43 - j));
            q1mrg[up] = min(vm, cm);
            const int ry = refl(ty0 - HALO + i, H);
            q1o0[up] = (ry * W + refl(tx0 - HALO + j,     W)) * 3;
            q1o1[up] = (ry * W + refl(tx0 - HALO + j + 1, W)) * 3;
            q1o2[up] = (ry * W + refl(tx0 - HALO + j + 2, W)) * 3;
            q1o3[up] = (ry * W + refl(tx0 - HALO + j + 3, W)) * 3;
        }
    }

    // ---- stage-2 2x2-block metadata: R,C in [0,22); i = 2R+2, j = 2C+2 ----
    // rb window rows 2R..2R+3, dwords d = 48R + C, d+1 (cols j-2..j+1).
    int s2lat_ = 0, s2rb_ = 0, s2mx_ = -1, s2mk_ = 0;
    if (tid < NB2) {
        const int R = tid / 22, C = tid - R * 22;
        const int i = 2 * R + 2, j = 2 * C + 2;
        s2lat_ = i * LRS + j;
        s2rb_  = 2 * R * RDW + C;        // dword index into rbt plane
        const int mxr = max(min(i - 2, 45 - i), min(i - 1, 44 - i));
        const int mxc = max(min(j - 2, 45 - j), min(j - 1, 44 - j));
        s2mx_ = min(mxr, mxc);
        const bool i0 = ((unsigned)(i     - HALO) < 32u);
        const bool i1 = ((unsigned)(i + 1 - HALO) < 32u);
        const bool j0 = ((unsigned)(j     - HALO) < 32u);
        const bool j1 = ((unsigned)(j + 1 - HALO) < 32u);
        s2mk_ = (i0 && j0 ? 1 : 0) | (i0 && j1 ? 2 : 0)
              | (i1 && j0 ? 4 : 0) | (i1 && j1 ? 8 : 0);
    }

    // ---- fused sub-iterations (2 barriers each) ----
    #pragma unroll
    for (int s = 0; s < K; ++s) {
        if (s >= m) break;

        // stage 1: rb = inp * rcp(conv(lat, k)) — span-4 quads, dy-symmetric:
        // rows i-1 and i+1 pre-summed (gk row0 == row2), 6 mult/px.
        #pragma unroll
        for (int up = 0; up < 2; ++up) {
            if (2 * s <= q1mrg[up]) {
                const int lo = q1lat[up];
                const int ro = q1rb[up];
                #pragma unroll
                for (int c = 0; c < 3; ++c) {
                    const float p0 = inp_n[q1o0[up] + c];
                    const float p1 = inp_n[q1o1[up] + c];
                    const float p2 = inp_n[q1o2[up] + c];
                    const float p3 = inp_n[q1o3[up] + c];
                    const float* lc = &lat[c * LPS + lo];
                    const float4 Fm = *(const float4*)(lc - LRS - 1);
                    const float2 Gm = *(const float2*)(lc - LRS + 3);
                    const float4 Fc = *(const float4*)(lc - 1);
                    const float2 Gc = *(const float2*)(lc + 3);
                    const float4 Fp = *(const float4*)(lc + LRS - 1);
                    const float2 Gp = *(const float2*)(lc + LRS + 3);
                    const float sx = Fm.x + Fp.x, sy = Fm.y + Fp.y;
                    const float sz = Fm.z + Fp.z, sw = Fm.w + Fp.w;
                    const float sgx = Gm.x + Gp.x, sgy = Gm.y + Gp.y;
                    const float w0 = k0w[c][0], w1 = k0w[c][1], w2 = k0w[c][2];
                    const float m0 = k1w[c][0], m1 = k1w[c][1], m2 = k1w[c][2];
                    float a0 = fmaf(w2, sz, fmaf(w1, sy, w0 * sx));
                    a0 = fmaf(m2, Fc.z, fmaf(m1, Fc.y, fmaf(m0, Fc.x, a0)));
                    float a1 = fmaf(w2, sw, fmaf(w1, sz, w0 * sy));
                    a1 = fmaf(m2, Fc.w, fmaf(m1, Fc.z, fmaf(m0, Fc.y, a1)));
                    float a2 = fmaf(w2, sgx, fmaf(w1, sw, w0 * sz));
                    a2 = fmaf(m2, Gc.x, fmaf(m1, Fc.w, fmaf(m0, Fc.z, a2)));
                    float a3 = fmaf(w2, sgy, fmaf(w1, sgx, w0 * sw));
                    a3 = fmaf(m2, Gc.y, fmaf(m1, Gc.x, fmaf(m0, Fc.w, a3)));
                    const float r0 = p0 * __builtin_amdgcn_rcpf(a0);
                    const float r1 = p1 * __builtin_amdgcn_rcpf(a1);
                    const float r2 = p2 * __builtin_amdgcn_rcpf(a2);
                    const float r3 = p3 * __builtin_amdgcn_rcpf(a3);
                    *(__half2*)&rbt[c * RPS + ro]     = __floats2half2_rn(r0, r1);
                    *(__half2*)&rbt[c * RPS + ro + 2] = __floats2half2_rn(r2, r3);
                }
            }
        }
        __syncthreads();

        // stage 2: e = conv(rb, kf); lat *= e; esum over interior.
        // 2x2 block: rb rows A,B,Cc,D (4 consecutive), dwords d,d+1 each.
        // Out row i:   dy-sum S = A + Cc (gkf row0==row2), mid = B.
        // Out row i+1: dy-sum T = B + D,                   mid = Cc.
        float esum = 0.f;
        if (2 * s <= s2mx_) {
            float t00 = 0.f, t01 = 0.f, t10 = 0.f, t11 = 0.f;
            #pragma unroll
            for (int c = 0; c < 3; ++c) {
                const unsigned* rp = (const unsigned*)&rbt[c * RPS] + s2rb_;
                const unsigned A0 = rp[0],           A1 = rp[1];
                const unsigned B0 = rp[RDW],         B1 = rp[RDW + 1];
                const unsigned C0 = rp[2 * RDW],     C1 = rp[2 * RDW + 1];
                const unsigned D0 = rp[3 * RDW],     D1 = rp[3 * RDW + 1];
                const unsigned S0 = hadd2u(A0, C0),  S1 = hadd2u(A1, C1);
                const unsigned T0 = hadd2u(B0, D0),  T1 = hadd2u(B1, D1);
                const float w0 = f0w[c][0], w1 = f0w[c][1], w2 = f0w[c][2];
                const float v0 = f1w[c][0], v1 = f1w[c][1], v2 = f1w[c][2];
                float e00 = 0.f, e01 = 0.f, e10 = 0.f, e11 = 0.f;
                fmix_l(e00, S0, w0); fmix_h(e00, S0, w1); fmix_l(e00, S1, w2);
                fmix_l(e00, B0, v0); fmix_h(e00, B0, v1); fmix_l(e00, B1, v2);
                fmix_h(e01, S0, w0); fmix_l(e01, S1, w1); fmix_h(e01, S1, w2);
                fmix_h(e01, B0, v0); fmix_l(e01, B1, v1); fmix_h(e01, B1, v2);
                fmix_l(e10, T0, w0); fmix_h(e10, T0, w1); fmix_l(e10, T1, w2);
                fmix_l(e10, C0, v0); fmix_h(e10, C0, v1); fmix_l(e10, C1, v2);
                fmix_h(e11, T0, w0); fmix_l(e11, T1, w1); fmix_h(e11, T1, w2);
                fmix_h(e11, C0, v0); fmix_l(e11, C1, v1); fmix_h(e11, C1, v2);
                float2* Lp0 = (float2*)&lat[c * LPS + s2lat_];
                float2* Lp1 = (float2*)&lat[c * LPS + s2lat_ + LRS];
                float2 l0 = *Lp0, l1 = *Lp1;
                l0.x *= e00; l0.y *= e01;
                l1.x *= e10; l1.y *= e11;
                *Lp0 = l0; *Lp1 = l1;
                t00 += e00; t01 += e01; t10 += e10; t11 += e11;
            }
            esum = ((s2mk_ & 1) ? t00 : 0.f) + ((s2mk_ & 2) ? t01 : 0.f)
                 + ((s2mk_ & 4) ? t10 : 0.f) + ((s2mk_ & 8) ? t11 : 0.f);
        }
        if (wr_part) {
            #pragma unroll
            for (int off = 32; off; off >>= 1) esum += __shfl_down(esum, off, 64);
            if (lane == 0) wred[wid] = esum;
        }
        __syncthreads();     // lat writes done AND wred ready
        if (wr_part && tid == 0) {
            float t = 0.f;
            #pragma unroll
            for (int w2 = 0; w2 < NWAVES; ++w2) t += wred[w2];
            part[(base + s) * NBLKS + b] = t;
        }
    }

    // ---- write interior [8,40)^2 to dst ----
    WRITE_INTERIOR();
}

extern "C" void kernel_launch(void* const* d_in, const int* in_sizes, int n_in,
                              void* d_out, int out_size, void* d_ws, size_t ws_size,
                              hipStream_t stream) {
    const float* inputs = (const float*)d_in[0];
    const float* gk     = (const float*)d_in[1];
    const float* gkf    = (const float*)d_in[2];
    float* out = (float*)d_out;

    // ws: [0 .. 128KB) iteration partials [30][1024] + running tmin word
    //     | buffer A | buffer B
    char* ws = (char*)d_ws;
    float* part = (float*)ws;
    float* A    = (float*)(ws + 131072);
    float* Bb   = (float*)(ws + 131072 + (size_t)TOTAL * sizeof(float));

    // period-3 schedule; X[g] = latent at start of group g. X[8] = out.
    const float* X[9] = { inputs, A, out, Bb, A, out, Bb, A, out };

    for (int g = 0; g < 9; ++g) {
        const float* s  = X[(g == 8) ? 7 : g];
        const float* sp = X[(g == 0) ? 0 : g - 1];
        float*       d  = (float*)((g == 8) ? X[8] : X[g + 1]);
        rl_group<<<NBLKS, BLK, 0, stream>>>(inputs, gk, gkf, s, sp, d, part, g);
    }
}